// Round 2
// baseline (997.561 us; speedup 1.0000x reference)
//
#include <hip/hip_runtime.h>
#include <stdint.h>

#define NQ 10000
#define NC 2048
#define NW 157           // ceil(10000/64)
#define IOU_TH 0.5f

// -------- ws layout (bytes) --------
// scores : [0,       40000)
// rank   : [40000,   80000)
// boxes4 : [80000,  240000)   10000*4 f32 (xyxy, clipped+scaled)
// sx1    : [240000, 280000)   sorted SoA
// sy1    : [280000, 320000)
// sx2    : [320000, 360000)
// sy2    : [360000, 400000)
// sarea  : [400000, 440000)
// order  : [440000, 480000)   sorted index -> original index
// mask   : [480000, 480000+10000*157*8 = 13,040,000)

__global__ __launch_bounds__(256) void k_scores(const float* __restrict__ logits,
        float* __restrict__ out_scores, float* __restrict__ out_labels,
        float* __restrict__ ws_scores) {
    int wave = threadIdx.x >> 6;
    int lane = threadIdx.x & 63;
    int q = blockIdx.x * 4 + wave;
    if (q >= NQ) return;
    const float* row = logits + (size_t)q * NC;
    float4 v[8];
    float m = -3.4e38f;
    int am = 0;
    #pragma unroll
    for (int k = 0; k < 8; k++) {
        int idx = k * 256 + lane * 4;
        v[k] = *(const float4*)(row + idx);
        // strict > keeps first occurrence within this lane's ascending indices
        if (v[k].x > m) { m = v[k].x; am = idx; }
        if (v[k].y > m) { m = v[k].y; am = idx + 1; }
        if (v[k].z > m) { m = v[k].z; am = idx + 2; }
        if (v[k].w > m) { m = v[k].w; am = idx + 3; }
    }
    #pragma unroll
    for (int off = 32; off >= 1; off >>= 1) {
        float om = __shfl_xor(m, off);
        int   oa = __shfl_xor(am, off);
        if (om > m || (om == m && oa < am)) { m = om; am = oa; }
    }
    float s = 0.f;
    #pragma unroll
    for (int k = 0; k < 8; k++) {
        s += expf(v[k].x - m);
        s += expf(v[k].y - m);
        s += expf(v[k].z - m);
        s += expf(v[k].w - m);
    }
    #pragma unroll
    for (int off = 32; off >= 1; off >>= 1) s += __shfl_xor(s, off);
    if (lane == 0) {
        float sc = 1.0f / s;           // max prob = exp(0)/sum = 1/sum
        out_scores[q] = sc;
        out_labels[q] = (float)am;
        ws_scores[q]  = sc;
    }
}

__global__ __launch_bounds__(256) void k_cls(const float* __restrict__ cls,
                                             float* __restrict__ out) {
    float m = -3.4e38f; int am = 0x7fffffff;
    for (int idx = threadIdx.x; idx < NC; idx += 256) {
        float x = cls[idx];
        if (x > m) { m = x; am = idx; }    // per-thread indices ascending
    }
    int lane = threadIdx.x & 63, wave = threadIdx.x >> 6;
    #pragma unroll
    for (int off = 32; off >= 1; off >>= 1) {
        float om = __shfl_xor(m, off); int oa = __shfl_xor(am, off);
        if (om > m || (om == m && oa < am)) { m = om; am = oa; }
    }
    __shared__ float sm[4]; __shared__ int sa[4];
    if (lane == 0) { sm[wave] = m; sa[wave] = am; }
    __syncthreads();
    if (threadIdx.x == 0) {
        for (int w = 1; w < 4; w++)
            if (sm[w] > m || (sm[w] == m && sa[w] < am)) { m = sm[w]; am = sa[w]; }
        out[0] = (float)am;
    }
}

__global__ __launch_bounds__(256) void k_boxes(const float* __restrict__ pb,
        const int* __restrict__ ts, float* __restrict__ out_boxes,
        float* __restrict__ boxes4, int* __restrict__ rank) {
    #pragma clang fp contract(off)
    int i = blockIdx.x * 256 + threadIdx.x;
    if (i >= NQ) return;
    rank[i] = 0;
    // target_sizes may be int64 (low/high word pairs) or int32; values in [480,1333)
    int a0 = ts[0], a1 = ts[1];
    int ih, iw;
    if (a1 == 0) { ih = a0; iw = ts[2]; } else { ih = a0; iw = a1; }
    float sh = (float)ih, sw = (float)iw;
    float4 b = *(const float4*)(pb + i * 4);
    float x1 = b.x - 0.5f * b.z;
    float y1 = b.y - 0.5f * b.w;
    float x2 = b.x + 0.5f * b.z;
    float y2 = b.y + 0.5f * b.w;
    x1 = fminf(fmaxf(x1, 0.f), 1.f) * sw;
    y1 = fminf(fmaxf(y1, 0.f), 1.f) * sh;
    x2 = fminf(fmaxf(x2, 0.f), 1.f) * sw;
    y2 = fminf(fmaxf(y2, 0.f), 1.f) * sh;
    float4 o = make_float4(x1, y1, x2, y2);
    *(float4*)(out_boxes + i * 4) = o;
    *(float4*)(boxes4 + i * 4) = o;
}

// rank[i] = #{j: s_j > s_i} + #{j: s_j == s_i && j < i}  == position in argsort(-s) (stable)
__global__ __launch_bounds__(256) void k_count(const float* __restrict__ scores,
                                               int* __restrict__ rank) {
    __shared__ float sc[2000];
    int jbase = blockIdx.y * 2000;
    int jn = min(2000, NQ - jbase);
    for (int t = threadIdx.x; t < jn; t += 256) sc[t] = scores[jbase + t];
    __syncthreads();
    int i = blockIdx.x * 256 + threadIdx.x;
    if (i >= NQ) return;
    float si = scores[i];
    int cnt = 0;
    for (int jj = 0; jj < jn; jj++) {
        float sj = sc[jj];
        int j = jbase + jj;
        cnt += (sj > si) || (sj == si && j < i);
    }
    if (cnt) atomicAdd(&rank[i], cnt);
}

__global__ __launch_bounds__(256) void k_scatter(const float* __restrict__ boxes4,
        const int* __restrict__ rank, int* __restrict__ order,
        float* __restrict__ sx1, float* __restrict__ sy1,
        float* __restrict__ sx2, float* __restrict__ sy2,
        float* __restrict__ sarea) {
    #pragma clang fp contract(off)
    int i = blockIdx.x * 256 + threadIdx.x;
    if (i >= NQ) return;
    int r = rank[i];
    order[r] = i;
    float4 b = *(const float4*)(boxes4 + i * 4);
    sx1[r] = b.x; sy1[r] = b.y; sx2[r] = b.z; sy2[r] = b.w;
    sarea[r] = fmaxf(b.z - b.x, 0.f) * fmaxf(b.w - b.y, 0.f);
}

// mask[i][cb] bit jj = (j>i) && IoU(i, j)>0.5, j = cb*64+jj (sorted order)
__global__ __launch_bounds__(64) void k_mask(const float* __restrict__ sx1,
        const float* __restrict__ sy1, const float* __restrict__ sx2,
        const float* __restrict__ sy2, const float* __restrict__ sarea,
        unsigned long long* __restrict__ mask) {
    #pragma clang fp contract(off)
    int rb = blockIdx.x, cb = blockIdx.y;
    if (cb < rb) return;
    int t = threadIdx.x;
    __shared__ float cx1[64], cy1[64], cx2[64], cy2[64], ca[64];
    int j0 = cb * 64 + t;
    if (j0 < NQ) { cx1[t]=sx1[j0]; cy1[t]=sy1[j0]; cx2[t]=sx2[j0]; cy2[t]=sy2[j0]; ca[t]=sarea[j0]; }
    __syncthreads();
    int i = rb * 64 + t;
    if (i >= NQ) return;
    float xi1 = sx1[i], yi1 = sy1[i], xi2 = sx2[i], yi2 = sy2[i], ai = sarea[i];
    int ncol = min(64, NQ - cb * 64);
    unsigned long long word = 0;
    for (int jj = 0; jj < ncol; jj++) {
        int j = cb * 64 + jj;
        float lx = fmaxf(xi1, cx1[jj]);
        float ly = fmaxf(yi1, cy1[jj]);
        float rx = fminf(xi2, cx2[jj]);
        float ry = fminf(yi2, cy2[jj]);
        float w = fmaxf(rx - lx, 0.f);
        float h = fmaxf(ry - ly, 0.f);
        float inter = w * h;
        float denom = (ai + ca[jj]) - inter;   // ref op order: (areas[i]+areas)-inter
        float iou = inter / denom;
        bool sup = (iou > IOU_TH) && (j > i);
        word |= ((unsigned long long)(sup ? 1u : 0u)) << jj;
    }
    mask[(size_t)i * NW + cb] = word;
}

// Single-wave sequential greedy reduce, v3.
// Lessons from v2's regression (420us):
//   * dynamic-count load loops defeat counted vmcnt -> ALL deferred loads are
//     now a STATIC 8-slot straight-line batch (branchless slot extraction;
//     empty slots re-load the last kept row: OR is idempotent, row 0 is
//     provably the first kept row so last_rp=row0 init is always safe).
//   * resolve state (cur/alive/kept/crit) is kept strictly SGPR-resident:
//     every input comes from readlane (uniform) or scalar constants, so the
//     greedy chain is s_ff1 + readlane x4 + s_or/s_andn2 (~40cy/step), not
//     VALU 64-bit emulation (~100cy/step).
//   * word c+1 contribution is gathered DURING the resolve walk (2 extra
//     readlanes per kept, off the dependency chain) -> no load on the
//     c -> c+1 critical path.
//   * bulk suffix (words >= c+2) deferred exactly 2 chunks (ping-pong PA/PB,
//     static binding) -> ~2 chunk-times of slack cover L3 latency.
//   * stale-word ORs (w <= c+1) are harmless: word w is only ever read at
//     chunk w, before any late OR lands. w2 is clamped for lanes >= 29 whose
//     r2 word is never read.
__global__ __launch_bounds__(64) void k_scan(const unsigned long long* __restrict__ mask,
        const int* __restrict__ order, float* __restrict__ out_keep) {
    const int lane = threadIdx.x & 63;
    uint64_t r0 = 0, r1 = 0, r2 = 0;     // removed words: lane, lane+64, lane+128
    const int w0 = lane, w1 = lane + 64;
    const int w2 = (lane + 128 < NW) ? (lane + 128) : 0;   // clamped; those lanes' r2 unused

    // ping-pong deferred-bulk buffers (static-indexed -> stay in VGPRs)
    uint64_t PA[8][3], PB[8][3];
    #pragma unroll
    for (int t = 0; t < 8; t++) {
        #pragma unroll
        for (int k = 0; k < 3; k++) { PA[t][k] = 0; PB[t][k] = 0; }
    }

    auto rl32 = [](uint32_t v, int b) -> uint32_t {
        return (uint32_t)__builtin_amdgcn_readlane((int)v, b);
    };

    // pipeline registers: diag word + order + crit column, for chunk c and c+1
    // cc (crit col) for chunk c: lane b holds mask[c*64+b][c+1]
    uint32_t dg_lo, dg_hi, dgN_lo, dgN_hi;
    uint64_t cc, ccN;
    int ord, ordN;
    {
        const unsigned long long* rp0 = mask + (size_t)lane * NW;
        uint64_t d0 = rp0[0];
        cc  = rp0[1];
        ord = order[lane];
        const unsigned long long* rp1 = mask + (size_t)(64 + lane) * NW;
        uint64_t d1 = rp1[1];
        ccN = rp1[2];
        ordN = order[64 + lane];
        dg_lo = (uint32_t)d0; dg_hi = (uint32_t)(d0 >> 32);
        dgN_lo = (uint32_t)d1; dgN_hi = (uint32_t)(d1 >> 32);
    }

    uint64_t A_prev = 0;                       // word-c contribution from chunk c-1's kept
    const unsigned long long* last_rp = mask;  // row 0 = first kept row (always valid dup)

    auto chunk = [&](int c, uint64_t (&P)[8][3]) {
        // ---- prefetch diag/ord/crit for chunk c+2 (2 chunks of slack) ----
        uint32_t dgT_lo = 0, dgT_hi = 0; uint64_t ccT = 0; int ordT = 0;
        if (c + 2 < NW) {
            int i2 = (c + 2) * 64 + lane;
            if (i2 < NQ) {
                const unsigned long long* rp = mask + (size_t)i2 * NW;
                uint64_t d = rp[c + 2];
                dgT_lo = (uint32_t)d; dgT_hi = (uint32_t)(d >> 32);
                ordT = order[i2];
                if (c + 3 < NW) ccT = rp[c + 3];
            }
        }

        // ---- consume bulk_{c-2} (issued 2 chunks ago, static count) ----
        {
            uint64_t a0 = 0, a1 = 0, a2 = 0;
            #pragma unroll
            for (int t = 0; t < 8; t++) { a0 |= P[t][0]; a1 |= P[t][1]; a2 |= P[t][2]; }
            r0 |= a0; r1 |= a1; r2 |= a2;
        }

        // ---- removed word for chunk c (uniform via readlane) ----
        int cl = c & 63;
        uint32_t rlo, rhi;
        if (c < 64)       { rlo = rl32((uint32_t)r0, cl); rhi = rl32((uint32_t)(r0 >> 32), cl); }
        else if (c < 128) { rlo = rl32((uint32_t)r1, cl); rhi = rl32((uint32_t)(r1 >> 32), cl); }
        else              { rlo = rl32((uint32_t)r2, cl); rhi = rl32((uint32_t)(r2 >> 32), cl); }
        uint64_t cur = (((uint64_t)rhi << 32) | rlo) | A_prev;
        int nvalid = min(64, NQ - c * 64);
        if (nvalid < 64) cur |= (~0ull) << nvalid;   // invalid tail = suppressed

        // ---- scalar greedy resolve; fold crit (word c+1) into the walk ----
        uint64_t alive = ~cur;
        uint64_t kept = 0, Ac = 0;
        while (alive) {
            int b = (int)__builtin_ctzll(alive);
            uint64_t d  = ((uint64_t)rl32(dg_hi, b) << 32) | rl32(dg_lo, b);
            uint64_t cv = ((uint64_t)rl32((uint32_t)(cc >> 32), b) << 32) | rl32((uint32_t)cc, b);
            kept  |= 1ull << b;
            cur   |= d;
            Ac    |= cv;                 // off the chain: does not feed alive
            alive &= ~(d | (1ull << b));
        }

        // ---- write keep for this chunk ----
        int i = c * 64 + lane;
        if (i < NQ) out_keep[ord] = ((cur >> lane) & 1ull) ? 0.f : 1.f;

        // ---- issue bulk_c (words >= c+2) into P: STATIC 8 slots, branchless ----
        uint64_t kmr = kept;
        #pragma unroll
        for (int t = 0; t < 8; t++) {
            int b = kmr ? (int)__builtin_ctzll(kmr) : 0;
            const unsigned long long* rp = kmr ? (mask + (size_t)(c * 64 + b) * NW) : last_rp;
            last_rp = rp;                 // no-op when kmr==0
            kmr &= kmr - 1;               // 0 stays 0
            P[t][0] = rp[w0]; P[t][1] = rp[w1]; P[t][2] = rp[w2];
        }

        // ---- rare overflow (kept > 8): exposed in-chunk batches ----
        while (kmr) {
            uint64_t t0 = 0, t1 = 0, t2 = 0;
            #pragma unroll
            for (int t = 0; t < 8; t++) {
                int b = kmr ? (int)__builtin_ctzll(kmr) : 0;
                const unsigned long long* rp = kmr ? (mask + (size_t)(c * 64 + b) * NW) : last_rp;
                last_rp = rp;
                kmr &= kmr - 1;
                t0 |= rp[w0]; t1 |= rp[w1]; t2 |= rp[w2];
            }
            r0 |= t0; r1 |= t1; r2 |= t2;
        }

        // ---- rotate pipeline state ----
        A_prev = Ac;
        dg_lo = dgN_lo; dg_hi = dgN_hi; cc = ccN; ord = ordN;
        dgN_lo = dgT_lo; dgN_hi = dgT_hi; ccN = ccT; ordN = ordT;
    };

    // unrolled by 2 so ping-pong buffer binding is static (registers, not scratch)
    for (int c = 0; c < NW; c += 2) {
        chunk(c, PA);
        if (c + 1 < NW) chunk(c + 1, PB);
    }
}

extern "C" void kernel_launch(void* const* d_in, const int* in_sizes, int n_in,
                              void* d_out, int out_size, void* d_ws, size_t ws_size,
                              hipStream_t stream) {
    const float* pred_logits = (const float*)d_in[0];
    const float* pred_boxes  = (const float*)d_in[1];
    const float* cls_logits  = (const float*)d_in[2];
    const int*   tsizes      = (const int*)d_in[3];

    float* out = (float*)d_out;
    float* out_scores = out;
    float* out_labels = out + 10000;
    float* out_boxes  = out + 20000;
    float* out_keep   = out + 60000;
    float* out_cls    = out + 70000;

    char* ws = (char*)d_ws;
    float* ws_scores = (float*)(ws + 0);
    int*   rank      = (int*)  (ws + 40000);
    float* boxes4    = (float*)(ws + 80000);
    float* sx1       = (float*)(ws + 240000);
    float* sy1       = (float*)(ws + 280000);
    float* sx2       = (float*)(ws + 320000);
    float* sy2       = (float*)(ws + 360000);
    float* sarea     = (float*)(ws + 400000);
    int*   order     = (int*)  (ws + 440000);
    unsigned long long* mask = (unsigned long long*)(ws + 480000);

    k_scores<<<2500, 256, 0, stream>>>(pred_logits, out_scores, out_labels, ws_scores);
    k_cls<<<1, 256, 0, stream>>>(cls_logits, out_cls);
    k_boxes<<<40, 256, 0, stream>>>(pred_boxes, tsizes, out_boxes, boxes4, rank);
    k_count<<<dim3(40, 5), 256, 0, stream>>>(ws_scores, rank);
    k_scatter<<<40, 256, 0, stream>>>(boxes4, rank, order, sx1, sy1, sx2, sy2, sarea);
    k_mask<<<dim3(157, 157), 64, 0, stream>>>(sx1, sy1, sx2, sy2, sarea, mask);
    k_scan<<<1, 64, 0, stream>>>(mask, order, out_keep);
}

// Round 3
// 610.677 us; speedup vs baseline: 1.6335x; 1.6335x over previous
//
#include <hip/hip_runtime.h>
#include <stdint.h>

#define NQ 10000
#define NC 2048
#define NW 157           // ceil(10000/64)
#define IOU_TH 0.5f

// -------- ws layout (bytes) --------
// scores : [0,       40000)
// rank   : [40000,   80000)
// boxes4 : [80000,  240000)   10000*4 f32 (xyxy, clipped+scaled)
// sx1    : [240000, 280000)   sorted SoA
// sy1    : [280000, 320000)
// sx2    : [320000, 360000)
// sy2    : [360000, 400000)
// sarea  : [400000, 440000)
// order  : [440000, 480000)   sorted index -> original index
// mask   : [480000, 480000+10000*157*8 = 13,040,000)

__global__ __launch_bounds__(256) void k_scores(const float* __restrict__ logits,
        float* __restrict__ out_scores, float* __restrict__ out_labels,
        float* __restrict__ ws_scores) {
    int wave = threadIdx.x >> 6;
    int lane = threadIdx.x & 63;
    int q = blockIdx.x * 4 + wave;
    if (q >= NQ) return;
    const float* row = logits + (size_t)q * NC;
    float4 v[8];
    float m = -3.4e38f;
    int am = 0;
    #pragma unroll
    for (int k = 0; k < 8; k++) {
        int idx = k * 256 + lane * 4;
        v[k] = *(const float4*)(row + idx);
        // strict > keeps first occurrence within this lane's ascending indices
        if (v[k].x > m) { m = v[k].x; am = idx; }
        if (v[k].y > m) { m = v[k].y; am = idx + 1; }
        if (v[k].z > m) { m = v[k].z; am = idx + 2; }
        if (v[k].w > m) { m = v[k].w; am = idx + 3; }
    }
    #pragma unroll
    for (int off = 32; off >= 1; off >>= 1) {
        float om = __shfl_xor(m, off);
        int   oa = __shfl_xor(am, off);
        if (om > m || (om == m && oa < am)) { m = om; am = oa; }
    }
    float s = 0.f;
    #pragma unroll
    for (int k = 0; k < 8; k++) {
        s += expf(v[k].x - m);
        s += expf(v[k].y - m);
        s += expf(v[k].z - m);
        s += expf(v[k].w - m);
    }
    #pragma unroll
    for (int off = 32; off >= 1; off >>= 1) s += __shfl_xor(s, off);
    if (lane == 0) {
        float sc = 1.0f / s;           // max prob = exp(0)/sum = 1/sum
        out_scores[q] = sc;
        out_labels[q] = (float)am;
        ws_scores[q]  = sc;
    }
}

__global__ __launch_bounds__(256) void k_cls(const float* __restrict__ cls,
                                             float* __restrict__ out) {
    float m = -3.4e38f; int am = 0x7fffffff;
    for (int idx = threadIdx.x; idx < NC; idx += 256) {
        float x = cls[idx];
        if (x > m) { m = x; am = idx; }    // per-thread indices ascending
    }
    int lane = threadIdx.x & 63, wave = threadIdx.x >> 6;
    #pragma unroll
    for (int off = 32; off >= 1; off >>= 1) {
        float om = __shfl_xor(m, off); int oa = __shfl_xor(am, off);
        if (om > m || (om == m && oa < am)) { m = om; am = oa; }
    }
    __shared__ float sm[4]; __shared__ int sa[4];
    if (lane == 0) { sm[wave] = m; sa[wave] = am; }
    __syncthreads();
    if (threadIdx.x == 0) {
        for (int w = 1; w < 4; w++)
            if (sm[w] > m || (sm[w] == m && sa[w] < am)) { m = sm[w]; am = sa[w]; }
        out[0] = (float)am;
    }
}

__global__ __launch_bounds__(256) void k_boxes(const float* __restrict__ pb,
        const int* __restrict__ ts, float* __restrict__ out_boxes,
        float* __restrict__ boxes4, int* __restrict__ rank) {
    #pragma clang fp contract(off)
    int i = blockIdx.x * 256 + threadIdx.x;
    if (i >= NQ) return;
    rank[i] = 0;
    // target_sizes may be int64 (low/high word pairs) or int32; values in [480,1333)
    int a0 = ts[0], a1 = ts[1];
    int ih, iw;
    if (a1 == 0) { ih = a0; iw = ts[2]; } else { ih = a0; iw = a1; }
    float sh = (float)ih, sw = (float)iw;
    float4 b = *(const float4*)(pb + i * 4);
    float x1 = b.x - 0.5f * b.z;
    float y1 = b.y - 0.5f * b.w;
    float x2 = b.x + 0.5f * b.z;
    float y2 = b.y + 0.5f * b.w;
    x1 = fminf(fmaxf(x1, 0.f), 1.f) * sw;
    y1 = fminf(fmaxf(y1, 0.f), 1.f) * sh;
    x2 = fminf(fmaxf(x2, 0.f), 1.f) * sw;
    y2 = fminf(fmaxf(y2, 0.f), 1.f) * sh;
    float4 o = make_float4(x1, y1, x2, y2);
    *(float4*)(out_boxes + i * 4) = o;
    *(float4*)(boxes4 + i * 4) = o;
}

// rank[i] = #{j: s_j > s_i} + #{j: s_j == s_i && j < i}  == position in argsort(-s) (stable)
__global__ __launch_bounds__(256) void k_count(const float* __restrict__ scores,
                                               int* __restrict__ rank) {
    __shared__ float sc[2000];
    int jbase = blockIdx.y * 2000;
    int jn = min(2000, NQ - jbase);
    for (int t = threadIdx.x; t < jn; t += 256) sc[t] = scores[jbase + t];
    __syncthreads();
    int i = blockIdx.x * 256 + threadIdx.x;
    if (i >= NQ) return;
    float si = scores[i];
    int cnt = 0;
    for (int jj = 0; jj < jn; jj++) {
        float sj = sc[jj];
        int j = jbase + jj;
        cnt += (sj > si) || (sj == si && j < i);
    }
    if (cnt) atomicAdd(&rank[i], cnt);
}

__global__ __launch_bounds__(256) void k_scatter(const float* __restrict__ boxes4,
        const int* __restrict__ rank, int* __restrict__ order,
        float* __restrict__ sx1, float* __restrict__ sy1,
        float* __restrict__ sx2, float* __restrict__ sy2,
        float* __restrict__ sarea) {
    #pragma clang fp contract(off)
    int i = blockIdx.x * 256 + threadIdx.x;
    if (i >= NQ) return;
    int r = rank[i];
    order[r] = i;
    float4 b = *(const float4*)(boxes4 + i * 4);
    sx1[r] = b.x; sy1[r] = b.y; sx2[r] = b.z; sy2[r] = b.w;
    sarea[r] = fmaxf(b.z - b.x, 0.f) * fmaxf(b.w - b.y, 0.f);
}

// mask[i][cb] bit jj = (j>i) && IoU(i, j)>0.5, j = cb*64+jj (sorted order)
__global__ __launch_bounds__(64) void k_mask(const float* __restrict__ sx1,
        const float* __restrict__ sy1, const float* __restrict__ sx2,
        const float* __restrict__ sy2, const float* __restrict__ sarea,
        unsigned long long* __restrict__ mask) {
    #pragma clang fp contract(off)
    int rb = blockIdx.x, cb = blockIdx.y;
    if (cb < rb) return;
    int t = threadIdx.x;
    __shared__ float cx1[64], cy1[64], cx2[64], cy2[64], ca[64];
    int j0 = cb * 64 + t;
    if (j0 < NQ) { cx1[t]=sx1[j0]; cy1[t]=sy1[j0]; cx2[t]=sx2[j0]; cy2[t]=sy2[j0]; ca[t]=sarea[j0]; }
    __syncthreads();
    int i = rb * 64 + t;
    if (i >= NQ) return;
    float xi1 = sx1[i], yi1 = sy1[i], xi2 = sx2[i], yi2 = sy2[i], ai = sarea[i];
    int ncol = min(64, NQ - cb * 64);
    unsigned long long word = 0;
    for (int jj = 0; jj < ncol; jj++) {
        int j = cb * 64 + jj;
        float lx = fmaxf(xi1, cx1[jj]);
        float ly = fmaxf(yi1, cy1[jj]);
        float rx = fminf(xi2, cx2[jj]);
        float ry = fminf(yi2, cy2[jj]);
        float w = fmaxf(rx - lx, 0.f);
        float h = fmaxf(ry - ly, 0.f);
        float inter = w * h;
        float denom = (ai + ca[jj]) - inter;   // ref op order: (areas[i]+areas)-inter
        float iou = inter / denom;
        bool sup = (iou > IOU_TH) && (j > i);
        word |= ((unsigned long long)(sup ? 1u : 0u)) << jj;
    }
    mask[(size_t)i * NW + cb] = word;
}

// Single-wave sequential greedy reduce, v4 = round-0 structure, spill-free.
// Post-mortem of v2/v3 regressions: the 2x8-row deferred buffers needed 96
// VGPRs live simultaneously but builds allocated 60-84 -> the buffers lived
// in SCRATCH (address-taken via lambda reference capture + default occupancy
// target). Every issue/consume was a hidden global-memory round trip.
// Fixes here, relative to round-0:
//   * ONE 8-row batch (48 VGPRs), consumed immediately -- never two batches
//     live at once.
//   * no lambdas touching arrays; straight-line unrolled, constant-indexed.
//   * __launch_bounds__(64, 1): single-wave kernel gets the full VGPR budget.
// Everything else identical to the round-0 (577us-total) version.
__global__ __launch_bounds__(64, 1) void k_scan(const unsigned long long* __restrict__ mask,
        const int* __restrict__ order, float* __restrict__ out_keep) {
    int lane = threadIdx.x & 63;
    uint64_t r0 = 0, r1 = 0, r2 = 0;     // removed words: lane, lane+64, lane+128
    const int w0 = lane, w1 = lane + 64, w2 = lane + 128;
    const bool w2v = (w2 < NW);

    // prefetch chunk 0's diag word + order
    uint32_t dg_lo, dg_hi;
    {
        uint64_t dg = mask[(size_t)lane * NW + 0];
        dg_lo = (uint32_t)dg; dg_hi = (uint32_t)(dg >> 32);
    }
    int ord = order[lane];

    for (int c = 0; c < NW; c++) {
        // ---- prefetch next chunk (k_mask outputs, never mutated) ----
        uint64_t dg_n = 0; int ord_n = 0;
        if (c + 1 < NW) {
            int i2 = (c + 1) * 64 + lane;
            if (i2 < NQ) {
                dg_n  = mask[(size_t)i2 * NW + (c + 1)];
                ord_n = order[i2];
            }
        }

        // ---- removed-in word for this chunk (scalar via readlane) ----
        int cl = c & 63;
        uint32_t rlo, rhi;
        if (c < 64) {
            rlo = __builtin_amdgcn_readlane((uint32_t)r0, cl);
            rhi = __builtin_amdgcn_readlane((uint32_t)(r0 >> 32), cl);
        } else if (c < 128) {
            rlo = __builtin_amdgcn_readlane((uint32_t)r1, cl);
            rhi = __builtin_amdgcn_readlane((uint32_t)(r1 >> 32), cl);
        } else {
            rlo = __builtin_amdgcn_readlane((uint32_t)r2, cl);
            rhi = __builtin_amdgcn_readlane((uint32_t)(r2 >> 32), cl);
        }
        uint64_t cur = ((uint64_t)rhi << 32) | rlo;
        int nvalid = min(64, NQ - c * 64);
        if (nvalid < 64) cur |= (~0ull) << nvalid;   // invalid tail = suppressed

        // ---- scalar greedy resolve over alive bits ----
        uint64_t alive = ~cur;
        uint64_t kept = 0;
        while (alive) {
            int b = (int)__builtin_ctzll(alive);
            uint32_t dlo = __builtin_amdgcn_readlane(dg_lo, b);
            uint32_t dhi = __builtin_amdgcn_readlane(dg_hi, b);
            uint64_t d = ((uint64_t)dhi << 32) | dlo;   // row b's diag word (bits > b only)
            kept  |= 1ull << b;
            cur   |= d;
            alive &= ~(d | (1ull << b));
        }

        // ---- write keep for this chunk ----
        int i = c * 64 + lane;
        if (i < NQ) out_keep[ord] = ((cur >> lane) & 1ull) ? 0.f : 1.f;

        // ---- OR kept rows' suffix words into the register bitmap ----
        // one 8-row batch per iteration: 24 loads in flight, then a single
        // wait + OR. Batch fits in 48 VGPRs; consumed before the next batch
        // so it can never spill.
        uint64_t kmr = kept;
        while (kmr) {
            uint64_t x0a = 0, x1a = 0, x2a = 0;
            uint64_t x0b = 0, x1b = 0, x2b = 0;
            uint64_t x0c = 0, x1c = 0, x2c = 0;
            uint64_t x0d = 0, x1d = 0, x2d = 0;
            uint64_t x0e = 0, x1e = 0, x2e = 0;
            uint64_t x0f = 0, x1f = 0, x2f = 0;
            uint64_t x0g = 0, x1g = 0, x2g = 0;
            uint64_t x0h = 0, x1h = 0, x2h = 0;
            if (kmr) {
                int b = (int)__builtin_ctzll(kmr); kmr &= kmr - 1;
                const unsigned long long* rp = mask + (size_t)(c * 64 + b) * NW;
                if (w0 > c)        x0a = rp[w0];
                if (w1 > c)        x1a = rp[w1];
                if (w2v && w2 > c) x2a = rp[w2];
            }
            if (kmr) {
                int b = (int)__builtin_ctzll(kmr); kmr &= kmr - 1;
                const unsigned long long* rp = mask + (size_t)(c * 64 + b) * NW;
                if (w0 > c)        x0b = rp[w0];
                if (w1 > c)        x1b = rp[w1];
                if (w2v && w2 > c) x2b = rp[w2];
            }
            if (kmr) {
                int b = (int)__builtin_ctzll(kmr); kmr &= kmr - 1;
                const unsigned long long* rp = mask + (size_t)(c * 64 + b) * NW;
                if (w0 > c)        x0c = rp[w0];
                if (w1 > c)        x1c = rp[w1];
                if (w2v && w2 > c) x2c = rp[w2];
            }
            if (kmr) {
                int b = (int)__builtin_ctzll(kmr); kmr &= kmr - 1;
                const unsigned long long* rp = mask + (size_t)(c * 64 + b) * NW;
                if (w0 > c)        x0d = rp[w0];
                if (w1 > c)        x1d = rp[w1];
                if (w2v && w2 > c) x2d = rp[w2];
            }
            if (kmr) {
                int b = (int)__builtin_ctzll(kmr); kmr &= kmr - 1;
                const unsigned long long* rp = mask + (size_t)(c * 64 + b) * NW;
                if (w0 > c)        x0e = rp[w0];
                if (w1 > c)        x1e = rp[w1];
                if (w2v && w2 > c) x2e = rp[w2];
            }
            if (kmr) {
                int b = (int)__builtin_ctzll(kmr); kmr &= kmr - 1;
                const unsigned long long* rp = mask + (size_t)(c * 64 + b) * NW;
                if (w0 > c)        x0f = rp[w0];
                if (w1 > c)        x1f = rp[w1];
                if (w2v && w2 > c) x2f = rp[w2];
            }
            if (kmr) {
                int b = (int)__builtin_ctzll(kmr); kmr &= kmr - 1;
                const unsigned long long* rp = mask + (size_t)(c * 64 + b) * NW;
                if (w0 > c)        x0g = rp[w0];
                if (w1 > c)        x1g = rp[w1];
                if (w2v && w2 > c) x2g = rp[w2];
            }
            if (kmr) {
                int b = (int)__builtin_ctzll(kmr); kmr &= kmr - 1;
                const unsigned long long* rp = mask + (size_t)(c * 64 + b) * NW;
                if (w0 > c)        x0h = rp[w0];
                if (w1 > c)        x1h = rp[w1];
                if (w2v && w2 > c) x2h = rp[w2];
            }
            r0 |= (x0a | x0b) | (x0c | x0d) | ((x0e | x0f) | (x0g | x0h));
            r1 |= (x1a | x1b) | (x1c | x1d) | ((x1e | x1f) | (x1g | x1h));
            r2 |= (x2a | x2b) | (x2c | x2d) | ((x2e | x2f) | (x2g | x2h));
        }

        dg_lo = (uint32_t)dg_n; dg_hi = (uint32_t)(dg_n >> 32); ord = ord_n;
    }
}

extern "C" void kernel_launch(void* const* d_in, const int* in_sizes, int n_in,
                              void* d_out, int out_size, void* d_ws, size_t ws_size,
                              hipStream_t stream) {
    const float* pred_logits = (const float*)d_in[0];
    const float* pred_boxes  = (const float*)d_in[1];
    const float* cls_logits  = (const float*)d_in[2];
    const int*   tsizes      = (const int*)d_in[3];

    float* out = (float*)d_out;
    float* out_scores = out;
    float* out_labels = out + 10000;
    float* out_boxes  = out + 20000;
    float* out_keep   = out + 60000;
    float* out_cls    = out + 70000;

    char* ws = (char*)d_ws;
    float* ws_scores = (float*)(ws + 0);
    int*   rank      = (int*)  (ws + 40000);
    float* boxes4    = (float*)(ws + 80000);
    float* sx1       = (float*)(ws + 240000);
    float* sy1       = (float*)(ws + 280000);
    float* sx2       = (float*)(ws + 320000);
    float* sy2       = (float*)(ws + 360000);
    float* sarea     = (float*)(ws + 400000);
    int*   order     = (int*)  (ws + 440000);
    unsigned long long* mask = (unsigned long long*)(ws + 480000);

    k_scores<<<2500, 256, 0, stream>>>(pred_logits, out_scores, out_labels, ws_scores);
    k_cls<<<1, 256, 0, stream>>>(cls_logits, out_cls);
    k_boxes<<<40, 256, 0, stream>>>(pred_boxes, tsizes, out_boxes, boxes4, rank);
    k_count<<<dim3(40, 5), 256, 0, stream>>>(ws_scores, rank);
    k_scatter<<<40, 256, 0, stream>>>(boxes4, rank, order, sx1, sy1, sx2, sy2, sarea);
    k_mask<<<dim3(157, 157), 64, 0, stream>>>(sx1, sy1, sx2, sy2, sarea, mask);
    k_scan<<<1, 64, 0, stream>>>(mask, order, out_keep);
}

// Round 4
// 497.310 us; speedup vs baseline: 2.0059x; 1.2280x over previous
//
#include <hip/hip_runtime.h>
#include <stdint.h>

#define NQ 10000
#define NC 2048
#define NW 157           // ceil(10000/64)
#define IOU_TH 0.5f

// -------- ws layout (bytes) --------
// scores : [0,       40000)
// rank   : [40000,   80000)
// boxes4 : [80000,  240000)   10000*4 f32 (xyxy, clipped+scaled)
// sx1    : [240000, 280000)   sorted SoA
// sy1    : [280000, 320000)
// sx2    : [320000, 360000)
// sy2    : [360000, 400000)
// sarea  : [400000, 440000)
// order  : [440000, 480000)   sorted index -> original index
// mask   : [480000, 480000+10000*157*8 = 13,040,000)

__global__ __launch_bounds__(256) void k_scores(const float* __restrict__ logits,
        float* __restrict__ out_scores, float* __restrict__ out_labels,
        float* __restrict__ ws_scores) {
    int wave = threadIdx.x >> 6;
    int lane = threadIdx.x & 63;
    int q = blockIdx.x * 4 + wave;
    if (q >= NQ) return;
    const float* row = logits + (size_t)q * NC;
    float4 v[8];
    float m = -3.4e38f;
    int am = 0;
    #pragma unroll
    for (int k = 0; k < 8; k++) {
        int idx = k * 256 + lane * 4;
        v[k] = *(const float4*)(row + idx);
        // strict > keeps first occurrence within this lane's ascending indices
        if (v[k].x > m) { m = v[k].x; am = idx; }
        if (v[k].y > m) { m = v[k].y; am = idx + 1; }
        if (v[k].z > m) { m = v[k].z; am = idx + 2; }
        if (v[k].w > m) { m = v[k].w; am = idx + 3; }
    }
    #pragma unroll
    for (int off = 32; off >= 1; off >>= 1) {
        float om = __shfl_xor(m, off);
        int   oa = __shfl_xor(am, off);
        if (om > m || (om == m && oa < am)) { m = om; am = oa; }
    }
    float s = 0.f;
    #pragma unroll
    for (int k = 0; k < 8; k++) {
        s += expf(v[k].x - m);
        s += expf(v[k].y - m);
        s += expf(v[k].z - m);
        s += expf(v[k].w - m);
    }
    #pragma unroll
    for (int off = 32; off >= 1; off >>= 1) s += __shfl_xor(s, off);
    if (lane == 0) {
        float sc = 1.0f / s;           // max prob = exp(0)/sum = 1/sum
        out_scores[q] = sc;
        out_labels[q] = (float)am;
        ws_scores[q]  = sc;
    }
}

__global__ __launch_bounds__(256) void k_cls(const float* __restrict__ cls,
                                             float* __restrict__ out) {
    float m = -3.4e38f; int am = 0x7fffffff;
    for (int idx = threadIdx.x; idx < NC; idx += 256) {
        float x = cls[idx];
        if (x > m) { m = x; am = idx; }    // per-thread indices ascending
    }
    int lane = threadIdx.x & 63, wave = threadIdx.x >> 6;
    #pragma unroll
    for (int off = 32; off >= 1; off >>= 1) {
        float om = __shfl_xor(m, off); int oa = __shfl_xor(am, off);
        if (om > m || (om == m && oa < am)) { m = om; am = oa; }
    }
    __shared__ float sm[4]; __shared__ int sa[4];
    if (lane == 0) { sm[wave] = m; sa[wave] = am; }
    __syncthreads();
    if (threadIdx.x == 0) {
        for (int w = 1; w < 4; w++)
            if (sm[w] > m || (sm[w] == m && sa[w] < am)) { m = sm[w]; am = sa[w]; }
        out[0] = (float)am;
    }
}

__global__ __launch_bounds__(256) void k_boxes(const float* __restrict__ pb,
        const int* __restrict__ ts, float* __restrict__ out_boxes,
        float* __restrict__ boxes4, int* __restrict__ rank) {
    #pragma clang fp contract(off)
    int i = blockIdx.x * 256 + threadIdx.x;
    if (i >= NQ) return;
    rank[i] = 0;
    // target_sizes may be int64 (low/high word pairs) or int32; values in [480,1333)
    int a0 = ts[0], a1 = ts[1];
    int ih, iw;
    if (a1 == 0) { ih = a0; iw = ts[2]; } else { ih = a0; iw = a1; }
    float sh = (float)ih, sw = (float)iw;
    float4 b = *(const float4*)(pb + i * 4);
    float x1 = b.x - 0.5f * b.z;
    float y1 = b.y - 0.5f * b.w;
    float x2 = b.x + 0.5f * b.z;
    float y2 = b.y + 0.5f * b.w;
    x1 = fminf(fmaxf(x1, 0.f), 1.f) * sw;
    y1 = fminf(fmaxf(y1, 0.f), 1.f) * sh;
    x2 = fminf(fmaxf(x2, 0.f), 1.f) * sw;
    y2 = fminf(fmaxf(y2, 0.f), 1.f) * sh;
    float4 o = make_float4(x1, y1, x2, y2);
    *(float4*)(out_boxes + i * 4) = o;
    *(float4*)(boxes4 + i * 4) = o;
}

// rank[i] = #{j: s_j > s_i} + #{j: s_j == s_i && j < i}  == position in argsort(-s) (stable)
__global__ __launch_bounds__(256) void k_count(const float* __restrict__ scores,
                                               int* __restrict__ rank) {
    __shared__ float sc[2000];
    int jbase = blockIdx.y * 2000;
    int jn = min(2000, NQ - jbase);
    for (int t = threadIdx.x; t < jn; t += 256) sc[t] = scores[jbase + t];
    __syncthreads();
    int i = blockIdx.x * 256 + threadIdx.x;
    if (i >= NQ) return;
    float si = scores[i];
    int cnt = 0;
    for (int jj = 0; jj < jn; jj++) {
        float sj = sc[jj];
        int j = jbase + jj;
        cnt += (sj > si) || (sj == si && j < i);
    }
    if (cnt) atomicAdd(&rank[i], cnt);
}

__global__ __launch_bounds__(256) void k_scatter(const float* __restrict__ boxes4,
        const int* __restrict__ rank, int* __restrict__ order,
        float* __restrict__ sx1, float* __restrict__ sy1,
        float* __restrict__ sx2, float* __restrict__ sy2,
        float* __restrict__ sarea) {
    #pragma clang fp contract(off)
    int i = blockIdx.x * 256 + threadIdx.x;
    if (i >= NQ) return;
    int r = rank[i];
    order[r] = i;
    float4 b = *(const float4*)(boxes4 + i * 4);
    sx1[r] = b.x; sy1[r] = b.y; sx2[r] = b.z; sy2[r] = b.w;
    sarea[r] = fmaxf(b.z - b.x, 0.f) * fmaxf(b.w - b.y, 0.f);
}

// mask[i][cb] bit jj = (j>i) && IoU(i, j)>0.5, j = cb*64+jj (sorted order)
__global__ __launch_bounds__(64) void k_mask(const float* __restrict__ sx1,
        const float* __restrict__ sy1, const float* __restrict__ sx2,
        const float* __restrict__ sy2, const float* __restrict__ sarea,
        unsigned long long* __restrict__ mask) {
    #pragma clang fp contract(off)
    int rb = blockIdx.x, cb = blockIdx.y;
    if (cb < rb) return;
    int t = threadIdx.x;
    __shared__ float cx1[64], cy1[64], cx2[64], cy2[64], ca[64];
    int j0 = cb * 64 + t;
    if (j0 < NQ) { cx1[t]=sx1[j0]; cy1[t]=sy1[j0]; cx2[t]=sx2[j0]; cy2[t]=sy2[j0]; ca[t]=sarea[j0]; }
    __syncthreads();
    int i = rb * 64 + t;
    if (i >= NQ) return;
    float xi1 = sx1[i], yi1 = sy1[i], xi2 = sx2[i], yi2 = sy2[i], ai = sarea[i];
    int ncol = min(64, NQ - cb * 64);
    unsigned long long word = 0;
    for (int jj = 0; jj < ncol; jj++) {
        int j = cb * 64 + jj;
        float lx = fmaxf(xi1, cx1[jj]);
        float ly = fmaxf(yi1, cy1[jj]);
        float rx = fminf(xi2, cx2[jj]);
        float ry = fminf(yi2, cy2[jj]);
        float w = fmaxf(rx - lx, 0.f);
        float h = fmaxf(ry - ly, 0.f);
        float inter = w * h;
        float denom = (ai + ca[jj]) - inter;   // ref op order: (areas[i]+areas)-inter
        float iou = inter / denom;
        bool sup = (iou > IOU_TH) && (j > i);
        word |= ((unsigned long long)(sup ? 1u : 0u)) << jj;
    }
    mask[(size_t)i * NW + cb] = word;
}

// Greedy reduce, v5: 4-wave cooperative, removed-bitmap in LDS.
// Why (post-mortems R0-R3): per-chunk cost pinned at ~2.2-2.5us regardless of
// load micro-scheduling -> the floor was a single wave serializing
// {resolve -> issue suffix loads -> vmcnt(0) drain (loads AND the keep
// scatter-store) -> next chunk}, 157 serial round trips.
// Structure here:
//   * wave 0: serial greedy resolve (SGPR-disciplined via readfirstlane/
//     readlane; diag word prefetched 1 chunk ahead, issued concurrent with
//     the gather so its drain overlaps gather latency).
//   * ALL 256 threads: parallel suffix gather. Lane t owns word c+1+t
//     (256 lanes >= 156 remaining words -> <=1 word each). Each lane loads
//     its word for every kept row (8-wide batch, uniform branches) and ORs
//     into rem[w] in LDS (owner-exclusive, no atomics). One memory-latency
//     period per chunk total, coalesced along row suffixes.
//   * keep words stashed in LDS; out_keep written in a parallel epilogue ->
//     no store drain inside the loop.
//   * ~50 VGPRs, no arrays, no register-batch buffers -> no spill risk.
__global__ __launch_bounds__(256, 1) void k_scan(const unsigned long long* __restrict__ mask,
        const int* __restrict__ order, float* __restrict__ out_keep) {
    __shared__ unsigned long long rem[NW];    // removed bitmap, word w = sorted rows [w*64, w*64+64)
    __shared__ unsigned long long keepw[NW];  // resolved (suppressed) word per chunk
    __shared__ unsigned long long sh_kept;    // kept mask of current chunk (broadcast)

    const int tid  = threadIdx.x;
    const int wave = tid >> 6;
    const int lane = tid & 63;

    for (int w = tid; w < NW; w += 256) rem[w] = 0;

    // wave 0 preloads chunk 0's diag words (lane l <- row l, word 0)
    uint32_t dg_lo = 0, dg_hi = 0;
    if (wave == 0) {
        uint64_t dg = mask[(size_t)lane * NW + 0];
        dg_lo = (uint32_t)dg; dg_hi = (uint32_t)(dg >> 32);
    }
    __syncthreads();

    for (int c = 0; c < NW; c++) {
        // ================= phase 1: serial resolve (wave 0 only) =================
        if (wave == 0) {
            // removed word c -> SGPRs (readfirstlane keeps the whole resolve scalar)
            uint64_t t64 = rem[c];
            uint32_t clo = (uint32_t)__builtin_amdgcn_readfirstlane((int)(uint32_t)t64);
            uint32_t chi = (uint32_t)__builtin_amdgcn_readfirstlane((int)(uint32_t)(t64 >> 32));
            uint64_t cur = ((uint64_t)chi << 32) | clo;

            int nvalid = min(64, NQ - c * 64);
            if (nvalid < 64) cur |= (~0ull) << nvalid;   // invalid tail = suppressed

            uint64_t alive = ~cur;
            uint64_t kept  = 0;
            while (alive) {
                int b = (int)__builtin_ctzll(alive);
                uint32_t dlo = (uint32_t)__builtin_amdgcn_readlane((int)dg_lo, b);
                uint32_t dhi = (uint32_t)__builtin_amdgcn_readlane((int)dg_hi, b);
                uint64_t d = ((uint64_t)dhi << 32) | dlo;   // row b's diag word (bits > b only)
                kept  |= 1ull << b;
                cur   |= d;
                alive &= ~(d | (1ull << b));
            }
            if (tid == 0) { sh_kept = kept; keepw[c] = cur; }
        }
        __syncthreads();   // publish sh_kept / keepw[c]

        // ================= phase 2: parallel suffix gather (all threads) =========
        // uniform kept mask (scalar loop control)
        uint64_t kt;
        {
            uint64_t t64 = sh_kept;
            uint32_t klo = (uint32_t)__builtin_amdgcn_readfirstlane((int)(uint32_t)t64);
            uint32_t khi = (uint32_t)__builtin_amdgcn_readfirstlane((int)(uint32_t)(t64 >> 32));
            kt = ((uint64_t)khi << 32) | klo;
        }

        // wave 0: prefetch next chunk's diag (drains at barrier 2, hidden by gather)
        uint64_t dg_n = 0;
        if (wave == 0 && c + 1 < NW) {
            int i2 = (c + 1) * 64 + lane;
            if (i2 < NQ) dg_n = mask[(size_t)i2 * NW + (c + 1)];
        }

        // lane t owns word w = c+1+t; loads every kept row's word w (8-wide batch)
        int w = c + 1 + tid;
        if (w < NW && kt) {
            const unsigned long long* base = mask + (size_t)c * 64 * NW + w;
            uint64_t acc = 0;
            uint64_t km = kt;
            while (km) {
                uint64_t a0 = 0, a1 = 0, a2 = 0, a3 = 0, a4 = 0, a5 = 0, a6 = 0, a7 = 0;
                if (km) { int r = (int)__builtin_ctzll(km); km &= km - 1; a0 = base[(size_t)r * NW]; }
                if (km) { int r = (int)__builtin_ctzll(km); km &= km - 1; a1 = base[(size_t)r * NW]; }
                if (km) { int r = (int)__builtin_ctzll(km); km &= km - 1; a2 = base[(size_t)r * NW]; }
                if (km) { int r = (int)__builtin_ctzll(km); km &= km - 1; a3 = base[(size_t)r * NW]; }
                if (km) { int r = (int)__builtin_ctzll(km); km &= km - 1; a4 = base[(size_t)r * NW]; }
                if (km) { int r = (int)__builtin_ctzll(km); km &= km - 1; a5 = base[(size_t)r * NW]; }
                if (km) { int r = (int)__builtin_ctzll(km); km &= km - 1; a6 = base[(size_t)r * NW]; }
                if (km) { int r = (int)__builtin_ctzll(km); km &= km - 1; a7 = base[(size_t)r * NW]; }
                acc |= (a0 | a1) | (a2 | a3) | ((a4 | a5) | (a6 | a7));
            }
            if (acc) rem[w] |= acc;    // owner-exclusive word: plain RMW
        }
        __syncthreads();   // gather complete -> rem[c+1] valid for next resolve

        if (wave == 0) { dg_lo = (uint32_t)dg_n; dg_hi = (uint32_t)(dg_n >> 32); }
    }

    // ================= epilogue: parallel keep writeback =================
    for (int si = tid; si < NQ; si += 256) {
        unsigned long long kw = keepw[si >> 6];
        out_keep[order[si]] = ((kw >> (si & 63)) & 1ull) ? 0.f : 1.f;
    }
}

extern "C" void kernel_launch(void* const* d_in, const int* in_sizes, int n_in,
                              void* d_out, int out_size, void* d_ws, size_t ws_size,
                              hipStream_t stream) {
    const float* pred_logits = (const float*)d_in[0];
    const float* pred_boxes  = (const float*)d_in[1];
    const float* cls_logits  = (const float*)d_in[2];
    const int*   tsizes      = (const int*)d_in[3];

    float* out = (float*)d_out;
    float* out_scores = out;
    float* out_labels = out + 10000;
    float* out_boxes  = out + 20000;
    float* out_keep   = out + 60000;
    float* out_cls    = out + 70000;

    char* ws = (char*)d_ws;
    float* ws_scores = (float*)(ws + 0);
    int*   rank      = (int*)  (ws + 40000);
    float* boxes4    = (float*)(ws + 80000);
    float* sx1       = (float*)(ws + 240000);
    float* sy1       = (float*)(ws + 280000);
    float* sx2       = (float*)(ws + 320000);
    float* sy2       = (float*)(ws + 360000);
    float* sarea     = (float*)(ws + 400000);
    int*   order     = (int*)  (ws + 440000);
    unsigned long long* mask = (unsigned long long*)(ws + 480000);

    k_scores<<<2500, 256, 0, stream>>>(pred_logits, out_scores, out_labels, ws_scores);
    k_cls<<<1, 256, 0, stream>>>(cls_logits, out_cls);
    k_boxes<<<40, 256, 0, stream>>>(pred_boxes, tsizes, out_boxes, boxes4, rank);
    k_count<<<dim3(40, 5), 256, 0, stream>>>(ws_scores, rank);
    k_scatter<<<40, 256, 0, stream>>>(boxes4, rank, order, sx1, sy1, sx2, sy2, sarea);
    k_mask<<<dim3(157, 157), 64, 0, stream>>>(sx1, sy1, sx2, sy2, sarea, mask);
    k_scan<<<1, 256, 0, stream>>>(mask, order, out_keep);
}

// Round 5
// 429.930 us; speedup vs baseline: 2.3203x; 1.1567x over previous
//
#include <hip/hip_runtime.h>
#include <stdint.h>

#define NQ 10000
#define NC 2048
#define NW 157           // ceil(10000/64)
#define IOU_TH 0.5f

// -------- ws layout (bytes) --------
// scores : [0,       40000)
// rank   : [40000,   80000)
// boxes4 : [80000,  240000)   10000*4 f32 (xyxy, clipped+scaled)
// sx1    : [240000, 280000)   sorted SoA
// sy1    : [280000, 320000)
// sx2    : [320000, 360000)
// sy2    : [360000, 400000)
// sarea  : [400000, 440000)
// order  : [440000, 480000)   sorted index -> original index
// mask   : [480000, 480000+10000*157*8 = 13,040,000)

__global__ __launch_bounds__(256) void k_scores(const float* __restrict__ logits,
        float* __restrict__ out_scores, float* __restrict__ out_labels,
        float* __restrict__ ws_scores) {
    int wave = threadIdx.x >> 6;
    int lane = threadIdx.x & 63;
    int q = blockIdx.x * 4 + wave;
    if (q >= NQ) return;
    const float* row = logits + (size_t)q * NC;
    float4 v[8];
    float m = -3.4e38f;
    int am = 0;
    #pragma unroll
    for (int k = 0; k < 8; k++) {
        int idx = k * 256 + lane * 4;
        v[k] = *(const float4*)(row + idx);
        // strict > keeps first occurrence within this lane's ascending indices
        if (v[k].x > m) { m = v[k].x; am = idx; }
        if (v[k].y > m) { m = v[k].y; am = idx + 1; }
        if (v[k].z > m) { m = v[k].z; am = idx + 2; }
        if (v[k].w > m) { m = v[k].w; am = idx + 3; }
    }
    #pragma unroll
    for (int off = 32; off >= 1; off >>= 1) {
        float om = __shfl_xor(m, off);
        int   oa = __shfl_xor(am, off);
        if (om > m || (om == m && oa < am)) { m = om; am = oa; }
    }
    float s = 0.f;
    #pragma unroll
    for (int k = 0; k < 8; k++) {
        s += expf(v[k].x - m);
        s += expf(v[k].y - m);
        s += expf(v[k].z - m);
        s += expf(v[k].w - m);
    }
    #pragma unroll
    for (int off = 32; off >= 1; off >>= 1) s += __shfl_xor(s, off);
    if (lane == 0) {
        float sc = 1.0f / s;           // max prob = exp(0)/sum = 1/sum
        out_scores[q] = sc;
        out_labels[q] = (float)am;
        ws_scores[q]  = sc;
    }
}

__global__ __launch_bounds__(256) void k_cls(const float* __restrict__ cls,
                                             float* __restrict__ out) {
    float m = -3.4e38f; int am = 0x7fffffff;
    for (int idx = threadIdx.x; idx < NC; idx += 256) {
        float x = cls[idx];
        if (x > m) { m = x; am = idx; }    // per-thread indices ascending
    }
    int lane = threadIdx.x & 63, wave = threadIdx.x >> 6;
    #pragma unroll
    for (int off = 32; off >= 1; off >>= 1) {
        float om = __shfl_xor(m, off); int oa = __shfl_xor(am, off);
        if (om > m || (om == m && oa < am)) { m = om; am = oa; }
    }
    __shared__ float sm[4]; __shared__ int sa[4];
    if (lane == 0) { sm[wave] = m; sa[wave] = am; }
    __syncthreads();
    if (threadIdx.x == 0) {
        for (int w = 1; w < 4; w++)
            if (sm[w] > m || (sm[w] == m && sa[w] < am)) { m = sm[w]; am = sa[w]; }
        out[0] = (float)am;
    }
}

__global__ __launch_bounds__(256) void k_boxes(const float* __restrict__ pb,
        const int* __restrict__ ts, float* __restrict__ out_boxes,
        float* __restrict__ boxes4, int* __restrict__ rank) {
    #pragma clang fp contract(off)
    int i = blockIdx.x * 256 + threadIdx.x;
    if (i >= NQ) return;
    rank[i] = 0;
    // target_sizes may be int64 (low/high word pairs) or int32; values in [480,1333)
    int a0 = ts[0], a1 = ts[1];
    int ih, iw;
    if (a1 == 0) { ih = a0; iw = ts[2]; } else { ih = a0; iw = a1; }
    float sh = (float)ih, sw = (float)iw;
    float4 b = *(const float4*)(pb + i * 4);
    float x1 = b.x - 0.5f * b.z;
    float y1 = b.y - 0.5f * b.w;
    float x2 = b.x + 0.5f * b.z;
    float y2 = b.y + 0.5f * b.w;
    x1 = fminf(fmaxf(x1, 0.f), 1.f) * sw;
    y1 = fminf(fmaxf(y1, 0.f), 1.f) * sh;
    x2 = fminf(fmaxf(x2, 0.f), 1.f) * sw;
    y2 = fminf(fmaxf(y2, 0.f), 1.f) * sh;
    float4 o = make_float4(x1, y1, x2, y2);
    *(float4*)(out_boxes + i * 4) = o;
    *(float4*)(boxes4 + i * 4) = o;
}

// rank[i] = #{j: s_j > s_i} + #{j: s_j == s_i && j < i}  == position in argsort(-s) (stable)
__global__ __launch_bounds__(256) void k_count(const float* __restrict__ scores,
                                               int* __restrict__ rank) {
    __shared__ float sc[2000];
    int jbase = blockIdx.y * 2000;
    int jn = min(2000, NQ - jbase);
    for (int t = threadIdx.x; t < jn; t += 256) sc[t] = scores[jbase + t];
    __syncthreads();
    int i = blockIdx.x * 256 + threadIdx.x;
    if (i >= NQ) return;
    float si = scores[i];
    int cnt = 0;
    for (int jj = 0; jj < jn; jj++) {
        float sj = sc[jj];
        int j = jbase + jj;
        cnt += (sj > si) || (sj == si && j < i);
    }
    if (cnt) atomicAdd(&rank[i], cnt);
}

__global__ __launch_bounds__(256) void k_scatter(const float* __restrict__ boxes4,
        const int* __restrict__ rank, int* __restrict__ order,
        float* __restrict__ sx1, float* __restrict__ sy1,
        float* __restrict__ sx2, float* __restrict__ sy2,
        float* __restrict__ sarea) {
    #pragma clang fp contract(off)
    int i = blockIdx.x * 256 + threadIdx.x;
    if (i >= NQ) return;
    int r = rank[i];
    order[r] = i;
    float4 b = *(const float4*)(boxes4 + i * 4);
    sx1[r] = b.x; sy1[r] = b.y; sx2[r] = b.z; sy2[r] = b.w;
    sarea[r] = fmaxf(b.z - b.x, 0.f) * fmaxf(b.w - b.y, 0.f);
}

// mask[i][cb] bit jj = (j>i) && IoU(i, j)>0.5, j = cb*64+jj (sorted order)
__global__ __launch_bounds__(64) void k_mask(const float* __restrict__ sx1,
        const float* __restrict__ sy1, const float* __restrict__ sx2,
        const float* __restrict__ sy2, const float* __restrict__ sarea,
        unsigned long long* __restrict__ mask) {
    #pragma clang fp contract(off)
    int rb = blockIdx.x, cb = blockIdx.y;
    if (cb < rb) return;
    int t = threadIdx.x;
    __shared__ float cx1[64], cy1[64], cx2[64], cy2[64], ca[64];
    int j0 = cb * 64 + t;
    if (j0 < NQ) { cx1[t]=sx1[j0]; cy1[t]=sy1[j0]; cx2[t]=sx2[j0]; cy2[t]=sy2[j0]; ca[t]=sarea[j0]; }
    __syncthreads();
    int i = rb * 64 + t;
    if (i >= NQ) return;
    float xi1 = sx1[i], yi1 = sy1[i], xi2 = sx2[i], yi2 = sy2[i], ai = sarea[i];
    int ncol = min(64, NQ - cb * 64);
    unsigned long long word = 0;
    for (int jj = 0; jj < ncol; jj++) {
        int j = cb * 64 + jj;
        float lx = fmaxf(xi1, cx1[jj]);
        float ly = fmaxf(yi1, cy1[jj]);
        float rx = fminf(xi2, cx2[jj]);
        float ry = fminf(yi2, cy2[jj]);
        float w = fmaxf(rx - lx, 0.f);
        float h = fmaxf(ry - ly, 0.f);
        float inter = w * h;
        float denom = (ai + ca[jj]) - inter;   // ref op order: (areas[i]+areas)-inter
        float iou = inter / denom;
        bool sup = (iou > IOU_TH) && (j > i);
        word |= ((unsigned long long)(sup ? 1u : 0u)) << jj;
    }
    mask[(size_t)i * NW + cb] = word;
}

// Greedy reduce, v6: 4-wave cooperative + software pipeline so NO global-memory
// latency sits on the per-chunk critical path.
// R4 post-mortem: gather (avg ~13 kept -> 2 serial 8-wide batch latencies) ran
// IN SERIES with resolve -> ~1.7us/chunk. Here:
//   * critical word c+1: wave 0 prefetches column mask[(c+1)*64+lane][c+1,c+2]
//     into LDS double-buffers (dgbuf=diag, ccbuf=next-crit) one iteration
//     ahead; after resolve, kept lanes atomicOr ccbuf[lane] into rem[c+1] --
//     pure LDS, no global load on the resolve(c)->resolve(c+1) path.
//   * bulk words >= c+2 of kept(c): waves 1-3 (thread t owns word c+2+(t-64);
//     192 threads >= 155 words). Loads issue in phase B into 16 NAMED regs
//     (padded with the first kept row -- OR-idempotent), consumed NEXT
//     iteration in phase A: the vmcnt wait lands with a full iteration of
//     slack. Overflow kept>16 (early chunks) uses the 8-wide batch in B.
//   * wave 0 issues dg/cc loads at top of A, stores to LDS at end of B:
//     its own resolve+critical (~800cy) hides that latency.
// Phase/race audit: A: wave0 reads rem[c], others atomicOr rem[w>=c+2] (from
// bulk(c-1): w >= (c-1)+2 = c+1; NO -- consumed pending pw was set from
// bulk(c-1) with w >= c+1? bulk(c-1) words start at (c-1)+2 = c+1. rem[c+1]
// write in A(c) vs resolve(c) read of rem[c]: different words, safe. B: wave0
// atomicOrs rem[c+1] + writes LDS slot (c+1)&1; others only read mask/issue
// loads. All rem[c+1] writers (bulk consume in A, critical in B) are barrier-
// separated from the A(c+1) read.
__global__ __launch_bounds__(256, 1) void k_scan(const unsigned long long* __restrict__ mask,
        const int* __restrict__ order, float* __restrict__ out_keep) {
    __shared__ unsigned long long rem[NW];    // removed bitmap, word w = sorted rows [w*64,w*64+64)
    __shared__ unsigned long long keepw[NW];  // resolved (suppressed) word per chunk
    __shared__ unsigned long long dgbuf[2][64]; // diag word, chunk parity buffers
    __shared__ unsigned long long ccbuf[2][64]; // critical column (word c+1), parity buffers
    __shared__ unsigned long long sh_kept;

    const int tid  = threadIdx.x;
    const int wave = tid >> 6;
    const int lane = tid & 63;

    for (int w = tid; w < NW; w += 256) rem[w] = 0;

    // prologue: wave 0 stages chunk 0's diag (word 0) + critical column (word 1)
    if (wave == 0) {
        const unsigned long long* rp = mask + (size_t)lane * NW;
        dgbuf[0][lane] = rp[0];
        ccbuf[0][lane] = rp[1];
    }
    __syncthreads();

    // per-thread pending bulk state (waves 1-3)
    uint64_t p0=0,p1=0,p2=0,p3=0,p4=0,p5=0,p6=0,p7=0;
    uint64_t p8=0,p9=0,p10=0,p11=0,p12=0,p13=0,p14=0,p15=0;
    uint64_t pextra = 0;
    int pw = -1;

    for (int c = 0; c < NW; c++) {
        // ======================= phase A =======================
        uint64_t dn = 0, ccn = 0;
        if (wave == 0) {
            // issue next chunk's diag + critical-column loads FIRST (latency
            // hidden under resolve + critical; stored to LDS at end of B)
            if (c + 1 < NW) {
                int i2 = (c + 1) * 64 + lane;
                if (i2 < NQ) {
                    const unsigned long long* rp = mask + (size_t)i2 * NW;
                    dn = rp[c + 1];
                    if (c + 2 < NW) ccn = rp[c + 2];
                }
            }
            // serial greedy resolve (SGPR-disciplined)
            uint64_t t64 = rem[c];
            uint32_t clo = (uint32_t)__builtin_amdgcn_readfirstlane((int)(uint32_t)t64);
            uint32_t chi = (uint32_t)__builtin_amdgcn_readfirstlane((int)(uint32_t)(t64 >> 32));
            uint64_t cur = ((uint64_t)chi << 32) | clo;
            int nvalid = min(64, NQ - c * 64);
            if (nvalid < 64) cur |= (~0ull) << nvalid;   // invalid tail = suppressed

            uint64_t dgv = dgbuf[c & 1][lane];
            uint32_t dvlo = (uint32_t)dgv, dvhi = (uint32_t)(dgv >> 32);

            uint64_t alive = ~cur;
            uint64_t kept  = 0;
            while (alive) {
                int b = (int)__builtin_ctzll(alive);
                uint32_t dlo = (uint32_t)__builtin_amdgcn_readlane((int)dvlo, b);
                uint32_t dhi = (uint32_t)__builtin_amdgcn_readlane((int)dvhi, b);
                uint64_t d = ((uint64_t)dhi << 32) | dlo;   // row b's diag word (bits > b only)
                kept  |= 1ull << b;
                cur   |= d;
                alive &= ~(d | (1ull << b));
            }
            if (tid == 0) { sh_kept = kept; keepw[c] = cur; }
        } else {
            // consume pending bulk(c-1): vmcnt wait lands here, ~1 iteration
            // after issue -> latency fully hidden
            if (pw >= 0) {
                uint64_t pacc = ((p0|p1)|(p2|p3)) | ((p4|p5)|(p6|p7));
                pacc |= ((p8|p9)|(p10|p11)) | ((p12|p13)|(p14|p15));
                pacc |= pextra;
                if (pacc) atomicOr(&rem[pw], (unsigned long long)pacc);
            }
            pw = -1;
        }
        __syncthreads();   // barrier 1: sh_kept / keepw[c] published

        // ======================= phase B =======================
        uint64_t kts;
        {
            uint64_t t64 = sh_kept;
            uint32_t klo = (uint32_t)__builtin_amdgcn_readfirstlane((int)(uint32_t)t64);
            uint32_t khi = (uint32_t)__builtin_amdgcn_readfirstlane((int)(uint32_t)(t64 >> 32));
            kts = ((uint64_t)khi << 32) | klo;
        }

        if (wave == 0) {
            if (c + 1 < NW) {
                // critical word c+1 from pre-staged LDS column: no global load
                uint64_t ccv = ccbuf[c & 1][lane];
                if ((kts >> lane) & 1ull) atomicOr(&rem[c + 1], (unsigned long long)ccv);
                // stage next chunk's buffers (waits on dn/ccn: ~800cy old)
                dgbuf[(c + 1) & 1][lane] = dn;
                if (c + 2 < NW) ccbuf[(c + 1) & 1][lane] = ccn;
            }
        } else {
            // bulk issue: thread t owns word w = c+2+(t-64)
            int w = c + 2 + (tid - 64);
            if (kts && w < NW) {
                const unsigned long long* base = mask + (size_t)(c * 64) * NW + w;
                uint64_t km = kts;
                int r_first = (int)__builtin_ctzll(km);
                int r;
                // 16 named slots, padded with r_first (OR-idempotent duplicate)
                r = km ? (int)__builtin_ctzll(km) : r_first; if (km) km &= km - 1; p0  = base[(size_t)r * NW];
                r = km ? (int)__builtin_ctzll(km) : r_first; if (km) km &= km - 1; p1  = base[(size_t)r * NW];
                r = km ? (int)__builtin_ctzll(km) : r_first; if (km) km &= km - 1; p2  = base[(size_t)r * NW];
                r = km ? (int)__builtin_ctzll(km) : r_first; if (km) km &= km - 1; p3  = base[(size_t)r * NW];
                r = km ? (int)__builtin_ctzll(km) : r_first; if (km) km &= km - 1; p4  = base[(size_t)r * NW];
                r = km ? (int)__builtin_ctzll(km) : r_first; if (km) km &= km - 1; p5  = base[(size_t)r * NW];
                r = km ? (int)__builtin_ctzll(km) : r_first; if (km) km &= km - 1; p6  = base[(size_t)r * NW];
                r = km ? (int)__builtin_ctzll(km) : r_first; if (km) km &= km - 1; p7  = base[(size_t)r * NW];
                r = km ? (int)__builtin_ctzll(km) : r_first; if (km) km &= km - 1; p8  = base[(size_t)r * NW];
                r = km ? (int)__builtin_ctzll(km) : r_first; if (km) km &= km - 1; p9  = base[(size_t)r * NW];
                r = km ? (int)__builtin_ctzll(km) : r_first; if (km) km &= km - 1; p10 = base[(size_t)r * NW];
                r = km ? (int)__builtin_ctzll(km) : r_first; if (km) km &= km - 1; p11 = base[(size_t)r * NW];
                r = km ? (int)__builtin_ctzll(km) : r_first; if (km) km &= km - 1; p12 = base[(size_t)r * NW];
                r = km ? (int)__builtin_ctzll(km) : r_first; if (km) km &= km - 1; p13 = base[(size_t)r * NW];
                r = km ? (int)__builtin_ctzll(km) : r_first; if (km) km &= km - 1; p14 = base[(size_t)r * NW];
                r = km ? (int)__builtin_ctzll(km) : r_first; if (km) km &= km - 1; p15 = base[(size_t)r * NW];
                // overflow kept>16 (early chunks): exposed 8-wide batches
                pextra = 0;
                while (km) {
                    uint64_t x0=0,x1=0,x2=0,x3=0,x4=0,x5=0,x6=0,x7=0;
                    if (km) { r=(int)__builtin_ctzll(km); km&=km-1; x0=base[(size_t)r*NW]; }
                    if (km) { r=(int)__builtin_ctzll(km); km&=km-1; x1=base[(size_t)r*NW]; }
                    if (km) { r=(int)__builtin_ctzll(km); km&=km-1; x2=base[(size_t)r*NW]; }
                    if (km) { r=(int)__builtin_ctzll(km); km&=km-1; x3=base[(size_t)r*NW]; }
                    if (km) { r=(int)__builtin_ctzll(km); km&=km-1; x4=base[(size_t)r*NW]; }
                    if (km) { r=(int)__builtin_ctzll(km); km&=km-1; x5=base[(size_t)r*NW]; }
                    if (km) { r=(int)__builtin_ctzll(km); km&=km-1; x6=base[(size_t)r*NW]; }
                    if (km) { r=(int)__builtin_ctzll(km); km&=km-1; x7=base[(size_t)r*NW]; }
                    pextra |= (x0|x1)|(x2|x3)|((x4|x5)|(x6|x7));
                }
                pw = w;
            } else {
                pw = -1; pextra = 0;
            }
        }
        __syncthreads();   // barrier 2: rem[c+1] complete; LDS buffers staged
    }

    // ================= epilogue: parallel keep writeback =================
    for (int si = tid; si < NQ; si += 256) {
        unsigned long long kw = keepw[si >> 6];
        out_keep[order[si]] = ((kw >> (si & 63)) & 1ull) ? 0.f : 1.f;
    }
}

extern "C" void kernel_launch(void* const* d_in, const int* in_sizes, int n_in,
                              void* d_out, int out_size, void* d_ws, size_t ws_size,
                              hipStream_t stream) {
    const float* pred_logits = (const float*)d_in[0];
    const float* pred_boxes  = (const float*)d_in[1];
    const float* cls_logits  = (const float*)d_in[2];
    const int*   tsizes      = (const int*)d_in[3];

    float* out = (float*)d_out;
    float* out_scores = out;
    float* out_labels = out + 10000;
    float* out_boxes  = out + 20000;
    float* out_keep   = out + 60000;
    float* out_cls    = out + 70000;

    char* ws = (char*)d_ws;
    float* ws_scores = (float*)(ws + 0);
    int*   rank      = (int*)  (ws + 40000);
    float* boxes4    = (float*)(ws + 80000);
    float* sx1       = (float*)(ws + 240000);
    float* sy1       = (float*)(ws + 280000);
    float* sx2       = (float*)(ws + 320000);
    float* sy2       = (float*)(ws + 360000);
    float* sarea     = (float*)(ws + 400000);
    int*   order     = (int*)  (ws + 440000);
    unsigned long long* mask = (unsigned long long*)(ws + 480000);

    k_scores<<<2500, 256, 0, stream>>>(pred_logits, out_scores, out_labels, ws_scores);
    k_cls<<<1, 256, 0, stream>>>(cls_logits, out_cls);
    k_boxes<<<40, 256, 0, stream>>>(pred_boxes, tsizes, out_boxes, boxes4, rank);
    k_count<<<dim3(40, 5), 256, 0, stream>>>(ws_scores, rank);
    k_scatter<<<40, 256, 0, stream>>>(boxes4, rank, order, sx1, sy1, sx2, sy2, sarea);
    k_mask<<<dim3(157, 157), 64, 0, stream>>>(sx1, sy1, sx2, sy2, sarea, mask);
    k_scan<<<1, 256, 0, stream>>>(mask, order, out_keep);
}